// Round 1
// baseline (4941.279 us; speedup 1.0000x reference)
//
#include <hip/hip_runtime.h>

typedef unsigned short u16;
typedef __attribute__((ext_vector_type(8))) short bf16x8;
typedef __attribute__((ext_vector_type(4))) float f32x4;
typedef __attribute__((ext_vector_type(4))) float fvec4;
typedef __attribute__((ext_vector_type(4))) unsigned short u16x4;

#define MFMA16(a, b, c) __builtin_amdgcn_mfma_f32_16x16x32_bf16((a), (b), (c), 0, 0, 0)

#define SEQ 4096
#define SCALE 0.07216878364870323f   // (192)^-0.5
#define LOGTHETA 9.210340371976184f  // ln(10000)

__device__ __forceinline__ u16 f2bf(float f) {
  union { float f; unsigned u; } c; c.f = f;
  unsigned u = c.u;
  unsigned r = (u + 0x7fffu + ((u >> 16) & 1u)) >> 16;  // RNE
  return (u16)r;
}
__device__ __forceinline__ float bf2f(u16 b) {
  union { unsigned u; float f; } c; c.u = ((unsigned)b) << 16;
  return c.f;
}

// ---------------- fp32 -> bf16 conversion (vectorized) ----------------
__global__ void cvt_bf16(const float* __restrict__ src, u16* __restrict__ dst, int n4) {
  int stride = gridDim.x * blockDim.x;
  for (int i = blockIdx.x * blockDim.x + threadIdx.x; i < n4; i += stride) {
    f32x4 v = ((const f32x4*)src)[i];
    u16x4 o;
    o[0] = f2bf(v[0]); o[1] = f2bf(v[1]); o[2] = f2bf(v[2]); o[3] = f2bf(v[3]);
    ((u16x4*)dst)[i] = o;
  }
}

// ---------------- transpose wkv_b nope block: wt[h][c][d] = w[h*256+d][c] ----------------
__global__ void trans_wkvb(const u16* __restrict__ w, u16* __restrict__ wt) {
  int stride = gridDim.x * blockDim.x;
  for (int i = blockIdx.x * blockDim.x + threadIdx.x; i < 16 * 512 * 128; i += stride) {
    int h = i >> 16;           // /65536
    int r = i & 65535;
    int c = r >> 7, d = r & 127;
    wt[i] = w[(h * 256 + d) * 512 + c];
  }
}

// ---------------- tiled transpose: vt[c][t] = kva[t*576 + c], c<512 ----------------
__global__ void trans_vt(const u16* __restrict__ kva, u16* __restrict__ vt) {
  __shared__ u16 tile[64][65];
  int c0 = blockIdx.x * 64;
  int t0 = blockIdx.y * 64;
  for (int k = 0; k < 4; k++) {
    int el = threadIdx.x + k * 256;  // 64x64/4 per pass? need 4096/256=16... fix below
    (void)el;
  }
  // 64*64 = 4096 elements, 256 threads -> 16 each
  for (int k = 0; k < 16; k++) {
    int el = threadIdx.x + k * 256;
    int r = el >> 6, c = el & 63;
    tile[r][c] = kva[(t0 + r) * 576 + c0 + c];
  }
  __syncthreads();
  for (int k = 0; k < 16; k++) {
    int el = threadIdx.x + k * 256;
    int r = el >> 6, c = el & 63;
    vt[(c0 + r) * 4096 + t0 + c] = tile[c][r];
  }
}

// ---------------- RMSNorm q (in-place, 4096 x 1536 bf16) ----------------
__global__ void rms_q_kernel(u16* __restrict__ qa, const float* __restrict__ w) {
  int row = blockIdx.x;
  u16* p = qa + row * 1536;
  float vals[6];
  float ss = 0.f;
#pragma unroll
  for (int k = 0; k < 6; k++) {
    float v = bf2f(p[threadIdx.x + k * 256]);
    vals[k] = v;
    ss += v * v;
  }
  for (int m = 1; m < 64; m <<= 1) ss += __shfl_xor(ss, m);
  __shared__ float red[4];
  int wid = threadIdx.x >> 6;
  if ((threadIdx.x & 63) == 0) red[wid] = ss;
  __syncthreads();
  float tot = red[0] + red[1] + red[2] + red[3];
  float rr = rsqrtf(tot / 1536.f + 1e-6f);
#pragma unroll
  for (int k = 0; k < 6; k++) {
    int i = threadIdx.x + k * 256;
    p[i] = f2bf(vals[k] * rr * w[i]);
  }
}

// ---------------- RMSNorm kv (cols 0..511) + rope k_pe (cols 512..575), in-place ----------------
__global__ void rms_kv_kernel(u16* __restrict__ kva, const float* __restrict__ w) {
  int t = blockIdx.x;
  u16* p = kva + t * 576;
  float v0 = bf2f(p[threadIdx.x]);
  float v1 = bf2f(p[threadIdx.x + 256]);
  float ss = v0 * v0 + v1 * v1;
  for (int m = 1; m < 64; m <<= 1) ss += __shfl_xor(ss, m);
  __shared__ float red[4];
  int wid = threadIdx.x >> 6;
  if ((threadIdx.x & 63) == 0) red[wid] = ss;
  __syncthreads();
  float tot = red[0] + red[1] + red[2] + red[3];
  float rr = rsqrtf(tot / 512.f + 1e-6f);
  p[threadIdx.x] = f2bf(v0 * rr * w[threadIdx.x]);
  p[threadIdx.x + 256] = f2bf(v1 * rr * w[threadIdx.x + 256]);
  if (threadIdx.x < 32) {
    int i = threadIdx.x;
    float x0 = bf2f(p[512 + 2 * i]);
    float x1 = bf2f(p[512 + 2 * i + 1]);
    float invf = expf(-((float)(2 * i) / 64.f) * LOGTHETA);
    float ang = (float)t * invf;
    float cs = cosf(ang), sn = sinf(ang);
    p[512 + 2 * i] = f2bf(x0 * cs - x1 * sn);
    p[512 + 2 * i + 1] = f2bf(x0 * sn + x1 * cs);
  }
}

// ---------------- rope q_pe: qb -> qcat[..., 512:576] ----------------
__global__ void rope_q_kernel(const u16* __restrict__ qb, u16* __restrict__ qcat) {
  int stride = gridDim.x * blockDim.x;
  for (int idx = blockIdx.x * blockDim.x + threadIdx.x; idx < 4096 * 512; idx += stride) {
    int s = idx >> 9;
    int r = idx & 511;
    int h = r >> 5, i = r & 31;
    float x0 = bf2f(qb[s * 3072 + h * 192 + 128 + 2 * i]);
    float x1 = bf2f(qb[s * 3072 + h * 192 + 128 + 2 * i + 1]);
    float invf = expf(-((float)(2 * i) / 64.f) * LOGTHETA);
    float ang = (float)s * invf;
    float cs = cosf(ang), sn = sinf(ang);
    qcat[s * 9216 + h * 576 + 512 + 2 * i] = f2bf(x0 * cs - x1 * sn);
    qcat[s * 9216 + h * 576 + 512 + 2 * i + 1] = f2bf(x0 * sn + x1 * cs);
  }
}

// ---------------- generic MFMA GEMM: C = A(M,K) @ W(N,K)^T, bf16 in, bf16/fp32 out --------------
// grid: (N/64, M/64, Z). block 256 = 4 waves; wave w does rows m0..m0+15, cols n0..n0+63.
template <bool OUTF32>
__launch_bounds__(256)
__global__ void gemm_bt(const u16* __restrict__ A, int lda, int az,
                        const u16* __restrict__ W, int ldw, int wz,
                        void* __restrict__ Cp, int ldc, int cz, int K) {
  int z = blockIdx.z;
  int wid = threadIdx.x >> 6, lane = threadIdx.x & 63;
  int quad = lane >> 4, l16 = lane & 15;
  int m0 = blockIdx.y * 64 + wid * 16;
  int n0 = blockIdx.x * 64;
  const u16* Ab = A + z * az + (m0 + l16) * lda + quad * 8;
  const u16* Wb = W + z * wz + (n0 + l16) * ldw + quad * 8;
  f32x4 acc0 = {0.f, 0.f, 0.f, 0.f};
  f32x4 acc1 = acc0, acc2 = acc0, acc3 = acc0;
  for (int k = 0; k < K; k += 32) {
    bf16x8 a = *(const bf16x8*)(Ab + k);
    bf16x8 w0 = *(const bf16x8*)(Wb + k);
    bf16x8 w1 = *(const bf16x8*)(Wb + 16 * ldw + k);
    bf16x8 w2 = *(const bf16x8*)(Wb + 32 * ldw + k);
    bf16x8 w3 = *(const bf16x8*)(Wb + 48 * ldw + k);
    acc0 = MFMA16(a, w0, acc0);
    acc1 = MFMA16(a, w1, acc1);
    acc2 = MFMA16(a, w2, acc2);
    acc3 = MFMA16(a, w3, acc3);
  }
  int row = m0 + quad * 4;
#pragma unroll
  for (int r = 0; r < 4; r++) {
    int cbase = z * cz + (row + r) * ldc + n0 + l16;
    if (OUTF32) {
      float* C = (float*)Cp;
      C[cbase] = acc0[r];
      C[cbase + 16] = acc1[r];
      C[cbase + 32] = acc2[r];
      C[cbase + 48] = acc3[r];
    } else {
      u16* C = (u16*)Cp;
      C[cbase] = f2bf(acc0[r]);
      C[cbase + 16] = f2bf(acc1[r]);
      C[cbase + 32] = f2bf(acc2[r]);
      C[cbase + 48] = f2bf(acc3[r]);
    }
  }
}

// ---------------- flash attention: per-wave 16 Q-rows, one head ----------------
// qcat: (4096, 16*576) bf16 ; kcat: (4096, 576) bf16 ; vt: (512, 4096) bf16
// ctx: (4096, 16*512) bf16
__launch_bounds__(256, 2)
__global__ void attn_kernel(const u16* __restrict__ qcat, const u16* __restrict__ kcat,
                            const u16* __restrict__ vt, u16* __restrict__ ctx) {
  int wid = threadIdx.x >> 6, lane = threadIdx.x & 63;
  int quad = lane >> 4, l16 = lane & 15;
  int gw = blockIdx.x * 4 + wid;
  int h = gw >> 8, qt = gw & 255;
  int q0 = qt << 4;
  __shared__ __align__(16) u16 plds[4][16][40];

  const u16* qb = qcat + (q0 + l16) * 9216 + h * 576 + quad * 8;
  const u16* vb = vt + l16 * 4096 + quad * 8;

  f32x4 zero = {0.f, 0.f, 0.f, 0.f};
  f32x4 o[32];
#pragma unroll
  for (int ct = 0; ct < 32; ct++) o[ct] = zero;
  float mi[4] = {-1e30f, -1e30f, -1e30f, -1e30f};
  float li[4] = {0.f, 0.f, 0.f, 0.f};

  int tmax = q0 + 15;
  for (int t0 = 0; t0 <= tmax; t0 += 32) {
    const u16* kb = kcat + (t0 + l16) * 576 + quad * 8;
    f32x4 s0 = zero, s1 = zero;
#pragma unroll
    for (int kk = 0; kk < 18; kk++) {
      bf16x8 a = *(const bf16x8*)(qb + kk * 32);
      bf16x8 b0 = *(const bf16x8*)(kb + kk * 32);
      bf16x8 b1 = *(const bf16x8*)(kb + 16 * 576 + kk * 32);
      s0 = MFMA16(a, b0, s0);
      s1 = MFMA16(a, b1, s1);
    }
    int tc0 = t0 + l16, tc1 = t0 + 16 + l16;
    float a4[4];
#pragma unroll
    for (int r = 0; r < 4; r++) {
      int mrow = q0 + quad * 4 + r;
      float v0 = (tc0 <= mrow) ? s0[r] * SCALE : -1e30f;
      float v1 = (tc1 <= mrow) ? s1[r] * SCALE : -1e30f;
      float mt = fmaxf(v0, v1);
      mt = fmaxf(mt, __shfl_xor(mt, 1));
      mt = fmaxf(mt, __shfl_xor(mt, 2));
      mt = fmaxf(mt, __shfl_xor(mt, 4));
      mt = fmaxf(mt, __shfl_xor(mt, 8));
      float mnew = fmaxf(mi[r], mt);
      float alpha = __expf(mi[r] - mnew);
      float e0 = __expf(v0 - mnew);
      float e1 = __expf(v1 - mnew);
      float rs = e0 + e1;
      rs += __shfl_xor(rs, 1);
      rs += __shfl_xor(rs, 2);
      rs += __shfl_xor(rs, 4);
      rs += __shfl_xor(rs, 8);
      li[r] = li[r] * alpha + rs;
      mi[r] = mnew;
      a4[r] = alpha;
      plds[wid][quad * 4 + r][l16] = f2bf(e0);
      plds[wid][quad * 4 + r][16 + l16] = f2bf(e1);
    }
    f32x4 av = {a4[0], a4[1], a4[2], a4[3]};
#pragma unroll
    for (int ct = 0; ct < 32; ct++) o[ct] *= av;
    __threadfence_block();  // LDS write -> cross-lane read ordering within the wave
    bf16x8 ap = *(const bf16x8*)(&plds[wid][l16][quad * 8]);
    const u16* vbt = vb + t0;
#pragma unroll
    for (int ct = 0; ct < 32; ct++) {
      bf16x8 bv = *(const bf16x8*)(vbt + ct * 16 * 4096);
      o[ct] = MFMA16(ap, bv, o[ct]);
    }
    __threadfence_block();  // protect plds against next-iter overwrite before ap read retires
  }
  f32x4 inv = {1.f / li[0], 1.f / li[1], 1.f / li[2], 1.f / li[3]};
#pragma unroll
  for (int ct = 0; ct < 32; ct++) {
    f32x4 val = o[ct] * inv;
    int base = (q0 + quad * 4) * 8192 + h * 512 + ct * 16 + l16;
    ctx[base] = f2bf(val[0]);
    ctx[base + 8192] = f2bf(val[1]);
    ctx[base + 2 * 8192] = f2bf(val[2]);
    ctx[base + 3 * 8192] = f2bf(val[3]);
  }
}

// ---------------- launch ----------------
extern "C" void kernel_launch(void* const* d_in, const int* in_sizes, int n_in,
                              void* d_out, int out_size, void* d_ws, size_t ws_size,
                              hipStream_t stream) {
  const float* x = (const float*)d_in[0];
  const float* wqa = (const float*)d_in[1];
  const float* qnw = (const float*)d_in[2];
  const float* wqb = (const float*)d_in[3];
  const float* wkva = (const float*)d_in[4];
  const float* kvnw = (const float*)d_in[5];
  const float* wkvb = (const float*)d_in[6];
  const float* wo = (const float*)d_in[7];

  u16* ws = (u16*)d_ws;
  // offsets in u16 elements
  u16* XB = ws;                        //  4096*2048
  u16* WQAB = ws + 8388608;            //  1536*2048
  u16* WQBB = ws + 11534336;           //  3072*1536
  u16* WKVAB = ws + 16252928;          //  576*2048
  u16* WKVBB = ws + 17432576;          //  4096*512
  u16* WKVBT = ws + 19529728;          //  16*512*128
  u16* WOB = ws + 20578304;            //  2048*2048
  u16* QA = ws + 24772608;             //  4096*1536
  u16* KVA = ws + 31064064;            //  4096*576
  u16* VT = ws + 33423360;             //  512*4096
  u16* QCAT = ws + 35520512;           //  4096*16*576
  u16* CTX = ws + 73269248;            //  4096*16*512  (end: 106,823,680 u16 = ~204 MiB)
  u16* QB = CTX;                       //  alias: 4096*3072, dead before attn writes CTX
  u16* VBUF = QCAT;                    //  alias: 4096*2048, dead (qcat) before K6 writes

  dim3 blk(256);

  // fp32 -> bf16
  cvt_bf16<<<1024, blk, 0, stream>>>(x, XB, 2097152);
  cvt_bf16<<<1024, blk, 0, stream>>>(wqa, WQAB, 786432);
  cvt_bf16<<<1024, blk, 0, stream>>>(wqb, WQBB, 1179648);
  cvt_bf16<<<1024, blk, 0, stream>>>(wkva, WKVAB, 294912);
  cvt_bf16<<<1024, blk, 0, stream>>>(wkvb, WKVBB, 524288);
  cvt_bf16<<<1024, blk, 0, stream>>>(wo, WOB, 1048576);
  trans_wkvb<<<1024, blk, 0, stream>>>(WKVBB, WKVBT);

  // q_a = x @ wq_a^T ; kv_a = x @ wkv_a^T
  gemm_bt<false><<<dim3(24, 64, 1), blk, 0, stream>>>(XB, 2048, 0, WQAB, 2048, 0, QA, 1536, 0, 2048);
  gemm_bt<false><<<dim3(9, 64, 1), blk, 0, stream>>>(XB, 2048, 0, WKVAB, 2048, 0, KVA, 576, 0, 2048);

  // norms + k rope, then V^T
  rms_q_kernel<<<4096, blk, 0, stream>>>(QA, qnw);
  rms_kv_kernel<<<4096, blk, 0, stream>>>(KVA, kvnw);
  trans_vt<<<dim3(8, 64), blk, 0, stream>>>(KVA, VT);

  // q = qn @ wq_b^T
  gemm_bt<false><<<dim3(48, 64, 1), blk, 0, stream>>>(QA, 1536, 0, WQBB, 1536, 0, QB, 3072, 0, 1536);

  // q_abs per head -> qcat[..., :512]
  gemm_bt<false><<<dim3(8, 64, 16), blk, 0, stream>>>(QB, 3072, 192, WKVBT, 128, 65536, QCAT, 9216, 576, 128);
  // rope(q_pe) -> qcat[..., 512:576]
  rope_q_kernel<<<2048, blk, 0, stream>>>(QB, QCAT);

  // flash attention
  attn_kernel<<<1024, blk, 0, stream>>>(QCAT, KVA, VT, CTX);

  // v per head: ctx @ wkv_b[h,128:,:]^T
  gemm_bt<false><<<dim3(2, 64, 16), blk, 0, stream>>>(CTX, 8192, 512, WKVBB + 65536, 512, 131072, VBUF, 2048, 128, 512);

  // out = v @ wo^T (fp32 out)
  gemm_bt<true><<<dim3(32, 64, 1), blk, 0, stream>>>(VBUF, 2048, 0, WOB, 2048, 0, d_out, 2048, 0, 2048);
}

// Round 2
// 2807.752 us; speedup vs baseline: 1.7599x; 1.7599x over previous
//
#include <hip/hip_runtime.h>

typedef unsigned short u16;
typedef __attribute__((ext_vector_type(8))) short bf16x8;
typedef __attribute__((ext_vector_type(4))) float f32x4;
typedef __attribute__((ext_vector_type(4))) unsigned short u16x4;

#define MFMA16(a, b, c) __builtin_amdgcn_mfma_f32_16x16x32_bf16((a), (b), (c), 0, 0, 0)

#define SEQ 4096
#define SCALE 0.07216878364870323f   // (192)^-0.5
#define LOGTHETA 9.210340371976184f  // ln(10000)

__device__ __forceinline__ u16 f2bf(float f) {
  union { float f; unsigned u; } c; c.f = f;
  unsigned u = c.u;
  unsigned r = (u + 0x7fffu + ((u >> 16) & 1u)) >> 16;  // RNE
  return (u16)r;
}
__device__ __forceinline__ float bf2f(u16 b) {
  union { unsigned u; float f; } c; c.u = ((unsigned)b) << 16;
  return c.f;
}

// ---------------- fp32 -> bf16 conversion (vectorized) ----------------
__global__ void cvt_bf16(const float* __restrict__ src, u16* __restrict__ dst, int n4) {
  int stride = gridDim.x * blockDim.x;
  for (int i = blockIdx.x * blockDim.x + threadIdx.x; i < n4; i += stride) {
    f32x4 v = ((const f32x4*)src)[i];
    u16x4 o;
    o[0] = f2bf(v[0]); o[1] = f2bf(v[1]); o[2] = f2bf(v[2]); o[3] = f2bf(v[3]);
    ((u16x4*)dst)[i] = o;
  }
}

// ---------------- transpose wkv_b nope block: wt[h][c][d] = w[h*256+d][c] ----------------
__global__ void trans_wkvb(const u16* __restrict__ w, u16* __restrict__ wt) {
  int stride = gridDim.x * blockDim.x;
  for (int i = blockIdx.x * blockDim.x + threadIdx.x; i < 16 * 512 * 128; i += stride) {
    int h = i >> 16;
    int r = i & 65535;
    int c = r >> 7, d = r & 127;
    wt[i] = w[(h * 256 + d) * 512 + c];
  }
}

// ---------------- tiled transpose: vt[c][t] = kva[t*576 + c], c<512 ----------------
__global__ void trans_vt(const u16* __restrict__ kva, u16* __restrict__ vt) {
  __shared__ u16 tile[64][65];
  int c0 = blockIdx.x * 64;
  int t0 = blockIdx.y * 64;
  for (int k = 0; k < 16; k++) {
    int el = threadIdx.x + k * 256;
    int r = el >> 6, c = el & 63;
    tile[r][c] = kva[(t0 + r) * 576 + c0 + c];
  }
  __syncthreads();
  for (int k = 0; k < 16; k++) {
    int el = threadIdx.x + k * 256;
    int r = el >> 6, c = el & 63;
    vt[(c0 + r) * 4096 + t0 + c] = tile[c][r];
  }
}

// ---------------- RMSNorm q (in-place, 4096 x 1536 bf16) ----------------
__global__ void rms_q_kernel(u16* __restrict__ qa, const float* __restrict__ w) {
  int row = blockIdx.x;
  u16* p = qa + row * 1536;
  float vals[6];
  float ss = 0.f;
#pragma unroll
  for (int k = 0; k < 6; k++) {
    float v = bf2f(p[threadIdx.x + k * 256]);
    vals[k] = v;
    ss += v * v;
  }
  for (int m = 1; m < 64; m <<= 1) ss += __shfl_xor(ss, m);
  __shared__ float red[4];
  int wid = threadIdx.x >> 6;
  if ((threadIdx.x & 63) == 0) red[wid] = ss;
  __syncthreads();
  float tot = red[0] + red[1] + red[2] + red[3];
  float rr = rsqrtf(tot / 1536.f + 1e-6f);
#pragma unroll
  for (int k = 0; k < 6; k++) {
    int i = threadIdx.x + k * 256;
    p[i] = f2bf(vals[k] * rr * w[i]);
  }
}

// ---------------- RMSNorm kv (cols 0..511) + rope k_pe (cols 512..575), in-place ----------------
__global__ void rms_kv_kernel(u16* __restrict__ kva, const float* __restrict__ w) {
  int t = blockIdx.x;
  u16* p = kva + t * 576;
  float v0 = bf2f(p[threadIdx.x]);
  float v1 = bf2f(p[threadIdx.x + 256]);
  float ss = v0 * v0 + v1 * v1;
  for (int m = 1; m < 64; m <<= 1) ss += __shfl_xor(ss, m);
  __shared__ float red[4];
  int wid = threadIdx.x >> 6;
  if ((threadIdx.x & 63) == 0) red[wid] = ss;
  __syncthreads();
  float tot = red[0] + red[1] + red[2] + red[3];
  float rr = rsqrtf(tot / 512.f + 1e-6f);
  p[threadIdx.x] = f2bf(v0 * rr * w[threadIdx.x]);
  p[threadIdx.x + 256] = f2bf(v1 * rr * w[threadIdx.x + 256]);
  if (threadIdx.x < 32) {
    int i = threadIdx.x;
    float x0 = bf2f(p[512 + 2 * i]);
    float x1 = bf2f(p[512 + 2 * i + 1]);
    float invf = expf(-((float)(2 * i) / 64.f) * LOGTHETA);
    float ang = (float)t * invf;
    float cs = cosf(ang), sn = sinf(ang);
    p[512 + 2 * i] = f2bf(x0 * cs - x1 * sn);
    p[512 + 2 * i + 1] = f2bf(x0 * sn + x1 * cs);
  }
}

// ---------------- rope q_pe: qb -> qcat[..., 512:576] ----------------
__global__ void rope_q_kernel(const u16* __restrict__ qb, u16* __restrict__ qcat) {
  int stride = gridDim.x * blockDim.x;
  for (int idx = blockIdx.x * blockDim.x + threadIdx.x; idx < 4096 * 512; idx += stride) {
    int s = idx >> 9;
    int r = idx & 511;
    int h = r >> 5, i = r & 31;
    float x0 = bf2f(qb[s * 3072 + h * 192 + 128 + 2 * i]);
    float x1 = bf2f(qb[s * 3072 + h * 192 + 128 + 2 * i + 1]);
    float invf = expf(-((float)(2 * i) / 64.f) * LOGTHETA);
    float ang = (float)s * invf;
    float cs = cosf(ang), sn = sinf(ang);
    qcat[s * 9216 + h * 576 + 512 + 2 * i] = f2bf(x0 * cs - x1 * sn);
    qcat[s * 9216 + h * 576 + 512 + 2 * i + 1] = f2bf(x0 * sn + x1 * cs);
  }
}

// ---------------- generic MFMA GEMM: C = A(M,K) @ W(N,K)^T, bf16 in, bf16/fp32 out --------------
template <bool OUTF32>
__launch_bounds__(256)
__global__ void gemm_bt(const u16* __restrict__ A, int lda, int az,
                        const u16* __restrict__ W, int ldw, int wz,
                        void* __restrict__ Cp, int ldc, int cz, int K) {
  int z = blockIdx.z;
  int wid = threadIdx.x >> 6, lane = threadIdx.x & 63;
  int quad = lane >> 4, l16 = lane & 15;
  int m0 = blockIdx.y * 64 + wid * 16;
  int n0 = blockIdx.x * 64;
  const u16* Ab = A + z * az + (m0 + l16) * lda + quad * 8;
  const u16* Wb = W + z * wz + (n0 + l16) * ldw + quad * 8;
  f32x4 acc0 = {0.f, 0.f, 0.f, 0.f};
  f32x4 acc1 = acc0, acc2 = acc0, acc3 = acc0;
  for (int k = 0; k < K; k += 32) {
    bf16x8 a = *(const bf16x8*)(Ab + k);
    bf16x8 w0 = *(const bf16x8*)(Wb + k);
    bf16x8 w1 = *(const bf16x8*)(Wb + 16 * ldw + k);
    bf16x8 w2 = *(const bf16x8*)(Wb + 32 * ldw + k);
    bf16x8 w3 = *(const bf16x8*)(Wb + 48 * ldw + k);
    acc0 = MFMA16(a, w0, acc0);
    acc1 = MFMA16(a, w1, acc1);
    acc2 = MFMA16(a, w2, acc2);
    acc3 = MFMA16(a, w3, acc3);
  }
  int row = m0 + quad * 4;
#pragma unroll
  for (int r = 0; r < 4; r++) {
    int cbase = z * cz + (row + r) * ldc + n0 + l16;
    if (OUTF32) {
      float* C = (float*)Cp;
      C[cbase] = acc0[r];
      C[cbase + 16] = acc1[r];
      C[cbase + 32] = acc2[r];
      C[cbase + 48] = acc3[r];
    } else {
      u16* C = (u16*)Cp;
      C[cbase] = f2bf(acc0[r]);
      C[cbase + 16] = f2bf(acc1[r]);
      C[cbase + 32] = f2bf(acc2[r]);
      C[cbase + 48] = f2bf(acc3[r]);
    }
  }
}

// ---------------- flash attention v2 ----------------
// Block = (head h, 64 q-rows). 4 waves, wave wid owns rows m0 = q0+wid*16 .. +15.
// Q pinned in VGPRs (18 bf16x8). K-tile (32 tokens x 576) staged in LDS via
// global_load_lds in chunk layout [kk(18)][half(2)][row(16) x 64B]. V read from
// global vt (L2-resident). Heavy-first block order for load balance.
__launch_bounds__(256, 2)
__global__ void attn_kernel(const u16* __restrict__ qcat, const u16* __restrict__ kcat,
                            const u16* __restrict__ vt, u16* __restrict__ ctx) {
  __shared__ __align__(16) u16 ldsk[36 * 512];     // 36 KB
  __shared__ __align__(16) u16 plds[4][16][40];    // 5 KB

  int wid = threadIdx.x >> 6, lane = threadIdx.x & 63;
  int quad = lane >> 4, l16 = lane & 15;
  int bx = blockIdx.x;
  int h = bx & 15;
  int qi = 63 - (bx >> 4);       // heavy-first
  int q0 = qi << 6;
  int m0 = q0 + wid * 16;

  // Q fragments pinned in registers
  bf16x8 q[18];
  {
    const u16* qb = qcat + (m0 + l16) * 9216 + h * 576 + quad * 8;
#pragma unroll
    for (int kk = 0; kk < 18; kk++) q[kk] = *(const bf16x8*)(qb + kk * 32);
  }

  f32x4 zero = {0.f, 0.f, 0.f, 0.f};
  f32x4 o[32];
#pragma unroll
  for (int ct = 0; ct < 32; ct++) o[ct] = zero;
  float mi[4] = {-1e30f, -1e30f, -1e30f, -1e30f};
  float li[4] = {0.f, 0.f, 0.f, 0.f};

  const u16* vbase = vt + l16 * 4096 + quad * 8;
  int srow = lane >> 2, ssub = lane & 3;          // staging: 16 rows x 4 chunks of 16B

  int nt = (q0 >> 5) + 2;                         // tiles of 32 tokens, covers q0+64
  for (int ti = 0; ti < nt; ti++) {
    int t0 = ti << 5;
    // ---- stage K tile: this wave loads chunks c = wid*9 .. wid*9+8 ----
#pragma unroll
    for (int j = 0; j < 9; j++) {
      int c = wid * 9 + j;
      int kk = c >> 1, half = c & 1;
      const u16* src = kcat + (t0 + half * 16 + srow) * 576 + kk * 32 + ssub * 8;
      __builtin_amdgcn_global_load_lds(
          (const __attribute__((address_space(1))) unsigned int*)src,
          (__attribute__((address_space(3))) unsigned int*)&ldsk[c * 512],
          16, 0, 0);
    }
    __syncthreads();   // drains vmcnt: staged K visible to all waves

    if (t0 <= m0 + 15) {   // wave-uniform: skip tiles past this wave's causal range
      // ---- QK^T from LDS ----
      f32x4 s0 = zero, s1 = zero;
#pragma unroll
      for (int kk = 0; kk < 18; kk++) {
        bf16x8 b0 = *(const bf16x8*)(&ldsk[(kk * 2 + 0) * 512 + l16 * 32 + quad * 8]);
        bf16x8 b1 = *(const bf16x8*)(&ldsk[(kk * 2 + 1) * 512 + l16 * 32 + quad * 8]);
        s0 = MFMA16(q[kk], b0, s0);
        s1 = MFMA16(q[kk], b1, s1);
      }
      // ---- online softmax ----
      int tc0 = t0 + l16, tc1 = t0 + 16 + l16;
      float a4[4];
#pragma unroll
      for (int r = 0; r < 4; r++) {
        int mrow = m0 + quad * 4 + r;
        float v0 = (tc0 <= mrow) ? s0[r] * SCALE : -1e30f;
        float v1 = (tc1 <= mrow) ? s1[r] * SCALE : -1e30f;
        float mt = fmaxf(v0, v1);
        mt = fmaxf(mt, __shfl_xor(mt, 1));
        mt = fmaxf(mt, __shfl_xor(mt, 2));
        mt = fmaxf(mt, __shfl_xor(mt, 4));
        mt = fmaxf(mt, __shfl_xor(mt, 8));
        float mnew = fmaxf(mi[r], mt);
        float alpha = __expf(mi[r] - mnew);
        float e0 = __expf(v0 - mnew);
        float e1 = __expf(v1 - mnew);
        float rs = e0 + e1;
        rs += __shfl_xor(rs, 1);
        rs += __shfl_xor(rs, 2);
        rs += __shfl_xor(rs, 4);
        rs += __shfl_xor(rs, 8);
        li[r] = li[r] * alpha + rs;
        mi[r] = mnew;
        a4[r] = alpha;
        plds[wid][quad * 4 + r][l16] = f2bf(e0);
        plds[wid][quad * 4 + r][16 + l16] = f2bf(e1);
      }
      f32x4 av = {a4[0], a4[1], a4[2], a4[3]};
#pragma unroll
      for (int ct = 0; ct < 32; ct++) o[ct] *= av;
      __threadfence_block();
      bf16x8 ap = *(const bf16x8*)(&plds[wid][l16][quad * 8]);
      const u16* vbt = vbase + t0;
#pragma unroll
      for (int ct = 0; ct < 32; ct++) {
        bf16x8 bv = *(const bf16x8*)(vbt + ct * 16 * 4096);
        o[ct] = MFMA16(ap, bv, o[ct]);
      }
      __threadfence_block();
    }
    __syncthreads();   // protect ldsk before next tile's staging
  }

  f32x4 inv = {1.f / li[0], 1.f / li[1], 1.f / li[2], 1.f / li[3]};
#pragma unroll
  for (int ct = 0; ct < 32; ct++) {
    f32x4 val = o[ct] * inv;
    int base = (m0 + quad * 4) * 8192 + h * 512 + ct * 16 + l16;
    ctx[base] = f2bf(val[0]);
    ctx[base + 8192] = f2bf(val[1]);
    ctx[base + 2 * 8192] = f2bf(val[2]);
    ctx[base + 3 * 8192] = f2bf(val[3]);
  }
}

// ---------------- launch ----------------
extern "C" void kernel_launch(void* const* d_in, const int* in_sizes, int n_in,
                              void* d_out, int out_size, void* d_ws, size_t ws_size,
                              hipStream_t stream) {
  const float* x = (const float*)d_in[0];
  const float* wqa = (const float*)d_in[1];
  const float* qnw = (const float*)d_in[2];
  const float* wqb = (const float*)d_in[3];
  const float* wkva = (const float*)d_in[4];
  const float* kvnw = (const float*)d_in[5];
  const float* wkvb = (const float*)d_in[6];
  const float* wo = (const float*)d_in[7];

  u16* ws = (u16*)d_ws;
  u16* XB = ws;                        //  4096*2048
  u16* WQAB = ws + 8388608;            //  1536*2048
  u16* WQBB = ws + 11534336;           //  3072*1536
  u16* WKVAB = ws + 16252928;          //  576*2048
  u16* WKVBB = ws + 17432576;          //  4096*512
  u16* WKVBT = ws + 19529728;          //  16*512*128
  u16* WOB = ws + 20578304;            //  2048*2048
  u16* QA = ws + 24772608;             //  4096*1536
  u16* KVA = ws + 31064064;            //  4096*576
  u16* VT = ws + 33423360;             //  512*4096
  u16* QCAT = ws + 35520512;           //  4096*16*576
  u16* CTX = ws + 73269248;            //  4096*16*512
  u16* QB = CTX;                       //  alias: dead before attn writes CTX
  u16* VBUF = QCAT;                    //  alias: qcat dead before v-GEMM writes

  dim3 blk(256);

  cvt_bf16<<<1024, blk, 0, stream>>>(x, XB, 2097152);
  cvt_bf16<<<1024, blk, 0, stream>>>(wqa, WQAB, 786432);
  cvt_bf16<<<1024, blk, 0, stream>>>(wqb, WQBB, 1179648);
  cvt_bf16<<<1024, blk, 0, stream>>>(wkva, WKVAB, 294912);
  cvt_bf16<<<1024, blk, 0, stream>>>(wkvb, WKVBB, 524288);
  cvt_bf16<<<1024, blk, 0, stream>>>(wo, WOB, 1048576);
  trans_wkvb<<<1024, blk, 0, stream>>>(WKVBB, WKVBT);

  gemm_bt<false><<<dim3(24, 64, 1), blk, 0, stream>>>(XB, 2048, 0, WQAB, 2048, 0, QA, 1536, 0, 2048);
  gemm_bt<false><<<dim3(9, 64, 1), blk, 0, stream>>>(XB, 2048, 0, WKVAB, 2048, 0, KVA, 576, 0, 2048);

  rms_q_kernel<<<4096, blk, 0, stream>>>(QA, qnw);
  rms_kv_kernel<<<4096, blk, 0, stream>>>(KVA, kvnw);
  trans_vt<<<dim3(8, 64), blk, 0, stream>>>(KVA, VT);

  gemm_bt<false><<<dim3(48, 64, 1), blk, 0, stream>>>(QA, 1536, 0, WQBB, 1536, 0, QB, 3072, 0, 1536);

  gemm_bt<false><<<dim3(8, 64, 16), blk, 0, stream>>>(QB, 3072, 192, WKVBT, 128, 65536, QCAT, 9216, 576, 128);
  rope_q_kernel<<<2048, blk, 0, stream>>>(QB, QCAT);

  attn_kernel<<<1024, blk, 0, stream>>>(QCAT, KVA, VT, CTX);

  gemm_bt<false><<<dim3(2, 64, 16), blk, 0, stream>>>(CTX, 8192, 512, WKVBB + 65536, 512, 131072, VBUF, 2048, 128, 512);

  gemm_bt<true><<<dim3(32, 64, 1), blk, 0, stream>>>(VBUF, 2048, 0, WOB, 2048, 0, d_out, 2048, 0, 2048);
}